// Round 1
// baseline (197.584 us; speedup 1.0000x reference)
//
#include <hip/hip_runtime.h>
#include <hip/hip_bf16.h>

typedef __attribute__((ext_vector_type(8))) short short8;
typedef __attribute__((ext_vector_type(4))) float float4v;

__device__ __forceinline__ unsigned short f2bf(float f) {
    // round-to-nearest-even fp32 -> bf16
    unsigned int u = __builtin_bit_cast(unsigned int, f);
    unsigned int lsb = (u >> 16) & 1u;
    u += 0x7fffu + lsb;
    return (unsigned short)(u >> 16);
}

// ---------------------------------------------------------------------------
// Kernel 1: LayerNorm + projections a = x@wa+ba (scaled by 1/S), b = x@wb+bb.
// Output layout: a_out/b_out [n][h][s] bf16  (n=256, h=32, s=64)
// One block per n (128 threads = 2 waves): wave 0 -> a, wave 1 -> b.
// Lane = s; fully per-lane serial (no cross-lane ops).
// ---------------------------------------------------------------------------
__global__ __launch_bounds__(128) void prep_ab(
    const float* __restrict__ msa, const float* __restrict__ ln_w,
    const float* __restrict__ ln_b, const float* __restrict__ wa,
    const float* __restrict__ ba, const float* __restrict__ wb,
    const float* __restrict__ bb, unsigned short* __restrict__ a_out,
    unsigned short* __restrict__ b_out)
{
    const int n = blockIdx.x;
    const int s = threadIdx.x & 63;
    const int which = threadIdx.x >> 6;           // 0 -> a, 1 -> b
    const float* __restrict__ w    = which ? wb : wa;
    const float* __restrict__ bias = which ? bb : ba;
    unsigned short* __restrict__ outp = which ? b_out : a_out;
    const float scale = which ? 1.0f : (1.0f / 64.0f);   // fold 1/S into a

    const float* __restrict__ row = msa + ((size_t)s * 256 + n) * 64;
    float x[64];
    float sum = 0.f;
    #pragma unroll
    for (int d = 0; d < 64; ++d) { x[d] = row[d]; sum += x[d]; }
    const float mu = sum * (1.f / 64.f);
    float var = 0.f;
    #pragma unroll
    for (int d = 0; d < 64; ++d) { float t = x[d] - mu; var += t * t; }
    const float rs = rsqrtf(var * (1.f / 64.f) + 1e-5f);

    float acc[32];
    #pragma unroll
    for (int h = 0; h < 32; ++h) acc[h] = 0.f;
    for (int d = 0; d < 64; ++d) {
        const float xn = (x[d] - mu) * rs * ln_w[d] + ln_b[d];
        #pragma unroll
        for (int h = 0; h < 32; ++h) acc[h] += xn * w[d * 32 + h];
    }
    #pragma unroll
    for (int h = 0; h < 32; ++h)
        outp[(size_t)(n * 32 + h) * 64 + s] = f2bf((acc[h] + bias[h]) * scale);
}

// ---------------------------------------------------------------------------
// Kernel 2: wo [1024][64] fp32 -> woT [64][1024] bf16 (stage-2 B^T layout)
// ---------------------------------------------------------------------------
__global__ __launch_bounds__(256) void prep_wo(const float* __restrict__ wo,
                                               unsigned short* __restrict__ woT)
{
    const int idx = blockIdx.x * 256 + threadIdx.x;  // 0..65535, coalesced read
    const int hk = idx >> 6, p = idx & 63;
    woT[(size_t)p * 1024 + hk] = f2bf(wo[idx]);
}

// ---------------------------------------------------------------------------
// Kernel 3: fused outer-product-mean + projection.
// Grid 64x64 blocks; block = 256 threads = 4 waves; tile = 4 i x 4 j = 16 pairs
// (a 128x128 tile of the [8192 x 8192] outer matrix, K = S = 64).
// Stage 1: wave w computes rows [w*32, w*32+32) x all 128 cols with
//          mfma_f32_16x16x32_bf16 (2 k-steps), writes bf16 M to LDS in
//          stage-2 A layout: ldsM[pair][h*32+k], row stride 1032 (pad:
//          516 dwords -> bank rotation, conflict-free ds_read_b128).
// Stage 2: wave w computes out[pairs][p = w*16 .. w*16+15] =
//          M[16x1024] @ wo[1024x64] via 32 k-steps of mfma_16x16x32.
// ---------------------------------------------------------------------------
__global__ __launch_bounds__(256) void fused_opm(
    const unsigned short* __restrict__ a_b, const unsigned short* __restrict__ b_b,
    const unsigned short* __restrict__ woT, const float* __restrict__ bo,
    float* __restrict__ out)
{
    __shared__ __align__(16) unsigned short ldsM[16][1032];

    const int bi = blockIdx.y, bj = blockIdx.x;   // i-block, j-block (4 each)
    const int w    = threadIdx.x >> 6;
    const int lane = threadIdx.x & 63;
    const int lm = lane & 15;                      // fragment row/col index
    const int q  = lane >> 4;                      // quad: k-octet selector

    // ---- stage 1: outer = a^T b over s ----
    float4v acc[2][8];
    #pragma unroll
    for (int r = 0; r < 2; ++r)
        #pragma unroll
        for (int c = 0; c < 8; ++c) acc[r][c] = (float4v){0.f, 0.f, 0.f, 0.f};

    #pragma unroll
    for (int ks = 0; ks < 2; ++ks) {
        const int s0 = ks * 32 + q * 8;
        short8 af[2];
        #pragma unroll
        for (int r = 0; r < 2; ++r) {
            const int row = w * 32 + r * 16 + lm;              // 0..127 = (i_local,h)
            af[r] = *(const short8*)(a_b + ((size_t)(bi * 128 + row)) * 64 + s0);
        }
        #pragma unroll
        for (int c = 0; c < 8; ++c) {
            const int col = c * 16 + lm;                       // 0..127 = (j_local,k)
            const short8 bf = *(const short8*)(b_b + ((size_t)(bj * 128 + col)) * 64 + s0);
            #pragma unroll
            for (int r = 0; r < 2; ++r)
                acc[r][c] = __builtin_amdgcn_mfma_f32_16x16x32_bf16(af[r], bf, acc[r][c], 0, 0, 0);
        }
    }

    // ---- C-tile -> LDS (bf16), stage-2 A layout: ldsM[pair][h*32+k] ----
    #pragma unroll
    for (int r = 0; r < 2; ++r) {
        #pragma unroll
        for (int c = 0; c < 8; ++c) {
            #pragma unroll
            for (int e = 0; e < 4; ++e) {
                const int row = w * 32 + r * 16 + q * 4 + e;   // (i_local,h)
                const int col = c * 16 + lm;                   // (j_local,k)
                const int lp = (row >> 5) * 4 + (col >> 5);    // pair 0..15
                ldsM[lp][(row & 31) * 32 + (col & 31)] = f2bf(acc[r][c][e]);
            }
        }
    }
    __syncthreads();

    // ---- stage 2: out[pair][p] = M[pair][:] @ wo[:, p] ----
    float4v acc2 = (float4v){0.f, 0.f, 0.f, 0.f};
    const unsigned short* __restrict__ wrow = woT + (size_t)(w * 16 + lm) * 1024;
    #pragma unroll 4
    for (int ks = 0; ks < 32; ++ks) {
        const int k0 = ks * 32 + q * 8;
        const short8 af = *(const short8*)(&ldsM[lm][k0]);
        const short8 bf = *(const short8*)(wrow + k0);
        acc2 = __builtin_amdgcn_mfma_f32_16x16x32_bf16(af, bf, acc2, 0, 0, 0);
    }

    const int p = w * 16 + lm;
    const float bias = bo[p];
    #pragma unroll
    for (int e = 0; e < 4; ++e) {
        const int lp = q * 4 + e;                              // pair 0..15
        const int i = bi * 4 + (lp >> 2);
        const int j = bj * 4 + (lp & 3);
        out[((size_t)i * 256 + j) * 64 + p] = acc2[e] + bias;
    }
}

// ---------------------------------------------------------------------------
extern "C" void kernel_launch(void* const* d_in, const int* in_sizes, int n_in,
                              void* d_out, int out_size, void* d_ws, size_t ws_size,
                              hipStream_t stream) {
    const float* msa  = (const float*)d_in[0];
    const float* ln_w = (const float*)d_in[1];
    const float* ln_b = (const float*)d_in[2];
    const float* wa   = (const float*)d_in[3];
    const float* ba   = (const float*)d_in[4];
    const float* wb   = (const float*)d_in[5];
    const float* bb   = (const float*)d_in[6];
    const float* wo   = (const float*)d_in[7];
    const float* bo   = (const float*)d_in[8];
    float* out = (float*)d_out;

    // workspace: a (1 MB) | b (1 MB) | woT (128 KB), all bf16
    unsigned short* a_ws = (unsigned short*)d_ws;
    unsigned short* b_ws = a_ws + 256 * 32 * 64;
    unsigned short* woT  = b_ws + 256 * 32 * 64;

    prep_ab<<<256, 128, 0, stream>>>(msa, ln_w, ln_b, wa, ba, wb, bb, a_ws, b_ws);
    prep_wo<<<256, 256, 0, stream>>>(wo, woT);
    fused_opm<<<dim3(64, 64), 256, 0, stream>>>(a_ws, b_ws, woT, bo, out);
}

// Round 2
// 123.988 us; speedup vs baseline: 1.5936x; 1.5936x over previous
//
#include <hip/hip_runtime.h>
#include <hip/hip_bf16.h>

typedef __attribute__((ext_vector_type(8))) short short8;
typedef __attribute__((ext_vector_type(4))) float float4v;

__device__ __forceinline__ unsigned short f2bf(float f) {
    // round-to-nearest-even fp32 -> bf16
    unsigned int u = __builtin_bit_cast(unsigned int, f);
    unsigned int lsb = (u >> 16) & 1u;
    u += 0x7fffu + lsb;
    return (unsigned short)(u >> 16);
}

__device__ __forceinline__ unsigned int pack2(float f0, float f1) {
    // round-half-up fp32x2 -> packed bf16x2 (cheap: 2 adds + shift/and/or)
    unsigned int u0 = __builtin_bit_cast(unsigned int, f0) + 0x8000u;
    unsigned int u1 = __builtin_bit_cast(unsigned int, f1) + 0x8000u;
    return (u0 >> 16) | (u1 & 0xffff0000u);
}

// ---------------------------------------------------------------------------
// prep_w: wo [1024][64] f32 -> woT [p][kk] bf16 with kk = k*32 + h
//         (contraction order (k,h) — must match fused LDS layout);
//         wa/wb [64][32] f32 -> wabT [h'][d] bf16 (h'<32: wa, h'>=32: wb)
// ---------------------------------------------------------------------------
__global__ __launch_bounds__(256) void prep_w(
    const float* __restrict__ wo, const float* __restrict__ wa,
    const float* __restrict__ wb, unsigned short* __restrict__ woT,
    unsigned short* __restrict__ wabT)
{
    const int idx = blockIdx.x * 256 + threadIdx.x;
    if (idx < 65536) {
        const int hk = idx >> 6, p = idx & 63;
        const int h = hk >> 5, k = hk & 31;
        woT[(size_t)p * 1024 + k * 32 + h] = f2bf(wo[idx]);
    } else if (idx < 65536 + 4096) {
        const int t = idx - 65536;
        const int hp = t >> 6, d = t & 63;
        const float v = (hp < 32) ? wa[d * 32 + hp] : wb[d * 32 + (hp - 32)];
        wabT[hp * 64 + d] = f2bf(v);
    }
}

// ---------------------------------------------------------------------------
// prep_ab: LayerNorm + [wa|wb] projection via MFMA.
// Block = 256 thr = 4 waves, one block per n; wave w handles s in [w*16,w*16+16).
// Lane (sl=lane>>2, dg=lane&3) loads 16 d's of row s0+sl (coalesced 64B runs),
// LN via width-4 shuffles, xn -> per-wave LDS tile (bf16, stride 72 shorts),
// then one 16x64x64 GEMM per wave: 8 MFMAs. Output a/b [n][h][s] bf16,
// vectorized b64 stores (e -> s contiguous). 1/S and biases folded in.
// ---------------------------------------------------------------------------
__global__ __launch_bounds__(256) void prep_ab(
    const float* __restrict__ msa, const float* __restrict__ ln_w,
    const float* __restrict__ ln_b, const float* __restrict__ ba,
    const float* __restrict__ bb, const unsigned short* __restrict__ wabT,
    unsigned short* __restrict__ a_out, unsigned short* __restrict__ b_out)
{
    __shared__ __align__(16) unsigned short xn[4][16 * 72];  // stride 72: 16B-aligned b128 reads, even bank spread
    const int n = blockIdx.x;
    const int w = threadIdx.x >> 6;
    const int lane = threadIdx.x & 63;
    const int s0 = w * 16;
    const int sl = lane >> 2, dg = lane & 3;
    const int lm = lane & 15, q = lane >> 4;

    const float* __restrict__ row = msa + ((size_t)((s0 + sl) * 256 + n)) * 64;
    float4 x[4];
    #pragma unroll
    for (int ii = 0; ii < 4; ++ii) x[ii] = *(const float4*)(row + ii * 16 + dg * 4);

    float s = 0.f;
    #pragma unroll
    for (int ii = 0; ii < 4; ++ii) s += (x[ii].x + x[ii].y) + (x[ii].z + x[ii].w);
    s += __shfl_xor(s, 1, 4);
    s += __shfl_xor(s, 2, 4);
    const float mu = s * (1.f / 64.f);

    float v = 0.f;
    #pragma unroll
    for (int ii = 0; ii < 4; ++ii) {
        float a0 = x[ii].x - mu, a1 = x[ii].y - mu, a2 = x[ii].z - mu, a3 = x[ii].w - mu;
        v += (a0 * a0 + a1 * a1) + (a2 * a2 + a3 * a3);
    }
    v += __shfl_xor(v, 1, 4);
    v += __shfl_xor(v, 2, 4);
    const float rs = rsqrtf(v * (1.f / 64.f) + 1e-5f);

    #pragma unroll
    for (int ii = 0; ii < 4; ++ii) {
        const float4 lw = *(const float4*)(ln_w + ii * 16 + dg * 4);
        const float4 lb = *(const float4*)(ln_b + ii * 16 + dg * 4);
        const float e0 = (x[ii].x - mu) * rs * lw.x + lb.x;
        const float e1 = (x[ii].y - mu) * rs * lw.y + lb.y;
        const float e2 = (x[ii].z - mu) * rs * lw.z + lb.z;
        const float e3 = (x[ii].w - mu) * rs * lw.w + lb.w;
        uint2 pk;
        pk.x = pack2(e0, e1);
        pk.y = pack2(e2, e3);
        *(uint2*)(&xn[w][sl * 72 + ii * 16 + dg * 4]) = pk;
    }
    __syncthreads();

    // A-fragments: rows m = lm <-> s = s0+m, k = d
    short8 afr[2];
    #pragma unroll
    for (int ks = 0; ks < 2; ++ks)
        afr[ks] = *(const short8*)(&xn[w][lm * 72 + ks * 32 + q * 8]);

    float4v acc[4];
    #pragma unroll
    for (int c = 0; c < 4; ++c) acc[c] = (float4v){0.f, 0.f, 0.f, 0.f};
    #pragma unroll
    for (int c = 0; c < 4; ++c) {
        #pragma unroll
        for (int ks = 0; ks < 2; ++ks) {
            const short8 bfr = *(const short8*)(wabT + (size_t)(c * 16 + lm) * 64 + ks * 32 + q * 8);
            acc[c] = __builtin_amdgcn_mfma_f32_16x16x32_bf16(afr[ks], bfr, acc[c], 0, 0, 0);
        }
    }

    // D: row = q*4+e -> s = s0+q*4+e (contiguous in e), col = lm -> h' = c*16+lm
    #pragma unroll
    for (int c = 0; c < 4; ++c) {
        const int hp = c * 16 + lm;
        const float bias = (hp < 32) ? ba[hp] : bb[hp - 32];
        const float scale = (hp < 32) ? (1.f / 64.f) : 1.f;  // fold 1/S into a
        unsigned short* __restrict__ dst = (hp < 32) ? a_out : b_out;
        const int h = hp & 31;
        const float e0 = (acc[c][0] + bias) * scale;
        const float e1 = (acc[c][1] + bias) * scale;
        const float e2 = (acc[c][2] + bias) * scale;
        const float e3 = (acc[c][3] + bias) * scale;
        uint2 pk;
        pk.x = pack2(e0, e1);
        pk.y = pack2(e2, e3);
        *(uint2*)(dst + ((size_t)(n * 32 + h)) * 64 + s0 + q * 4) = pk;
    }
}

// ---------------------------------------------------------------------------
// fused_opm v2: 512 blocks x 256 thr (4 waves); block b: bi = b>>3 fixed,
// loops 8 bj tiles. Per 128x128 outer tile (16 (i,j) pairs, K=S=64):
//   stage 1: wave w computes rows [w*32,w*32+32) x 128 cols (32 MFMAs, two
//            4-col halves to cap VGPRs), packs C to LDS bf16 in layout
//            M[pair][k*40 + h] (pair stride 1272 shorts): vectorized b64
//            writes, 16B-aligned b128 reads, even bank spread.
//   stage 2: A = register-resident woT fragments (loaded ONCE per block:
//            wave w holds rows p=w*16+lm, 32 frags = 128 VGPRs), B = M from
//            LDS. D rows = p -> contiguous float4 stores to out.
// woT L2 traffic: 512 MB -> 64 MB; no global loads inside stage 2.
// ---------------------------------------------------------------------------
__global__ __launch_bounds__(256, 2) void fused_opm(
    const unsigned short* __restrict__ a_b, const unsigned short* __restrict__ b_b,
    const unsigned short* __restrict__ woT, const float* __restrict__ bo,
    float* __restrict__ out)
{
    __shared__ __align__(16) unsigned short ldsM[16 * 1272];

    const int b = blockIdx.x;
    const int bi = b >> 3;
    const int bj0 = (b & 7) << 3;
    const int w = threadIdx.x >> 6;
    const int lane = threadIdx.x & 63;
    const int lm = lane & 15, q = lane >> 4;

    // hoisted a-fragments (bi fixed for whole block): rows (i=bi*4+w, h=r*16+lm)
    short8 af[2][2];
    #pragma unroll
    for (int r = 0; r < 2; ++r)
        #pragma unroll
        for (int ks = 0; ks < 2; ++ks)
            af[r][ks] = *(const short8*)(a_b + ((size_t)(bi * 128 + w * 32 + r * 16 + lm)) * 64 + ks * 32 + q * 8);

    // register-resident woT A-fragments: rows p = w*16+lm, kk = ks*32+q*8+j
    short8 wf[32];
    #pragma unroll
    for (int ks = 0; ks < 32; ++ks)
        wf[ks] = *(const short8*)(woT + ((size_t)(w * 16 + lm)) * 1024 + ks * 32 + q * 8);

    const float4 bo4 = *(const float4*)(bo + w * 16 + q * 4);
    const int i = bi * 4 + (lm >> 2);   // pair = lm = i_loc*4 + j_loc
    const int jb = lm & 3;

    for (int t = 0; t < 8; ++t) {
        const int bj = bj0 + t;

        // ---- stage 1: outer tile -> LDS (two halves of 4 col-tiles) ----
        #pragma unroll
        for (int half = 0; half < 2; ++half) {
            short8 bf[4][2];
            #pragma unroll
            for (int c2 = 0; c2 < 4; ++c2)
                #pragma unroll
                for (int ks = 0; ks < 2; ++ks) {
                    const int c = half * 4 + c2;
                    bf[c2][ks] = *(const short8*)(b_b + ((size_t)(bj * 128 + c * 16 + lm)) * 64 + ks * 32 + q * 8);
                }
            float4v acc1[2][4];
            #pragma unroll
            for (int r = 0; r < 2; ++r)
                #pragma unroll
                for (int c2 = 0; c2 < 4; ++c2) acc1[r][c2] = (float4v){0.f, 0.f, 0.f, 0.f};
            #pragma unroll
            for (int c2 = 0; c2 < 4; ++c2)
                #pragma unroll
                for (int ks = 0; ks < 2; ++ks)
                    #pragma unroll
                    for (int r = 0; r < 2; ++r)
                        acc1[r][c2] = __builtin_amdgcn_mfma_f32_16x16x32_bf16(af[r][ks], bf[c2][ks], acc1[r][c2], 0, 0, 0);

            // C: row = w*32+r*16+q*4+e -> (i_loc=w, h), col = c*16+lm -> (j_loc=c>>1, k)
            #pragma unroll
            for (int r = 0; r < 2; ++r)
                #pragma unroll
                for (int c2 = 0; c2 < 4; ++c2) {
                    const int c = half * 4 + c2;
                    const int pair = w * 4 + (c >> 1);
                    const int k = ((c & 1) << 4) + lm;
                    const int h0 = r * 16 + q * 4;
                    uint2 pk;
                    pk.x = pack2(acc1[r][c2][0], acc1[r][c2][1]);
                    pk.y = pack2(acc1[r][c2][2], acc1[r][c2][3]);
                    *(uint2*)(ldsM + pair * 1272 + k * 40 + h0) = pk;
                }
        }
        __syncthreads();

        // ---- stage 2: out[p][pair] = woT[p][:] . M[pair][:] ----
        float4v acc2 = (float4v){0.f, 0.f, 0.f, 0.f};
        #pragma unroll
        for (int ks = 0; ks < 32; ++ks) {
            const short8 mf = *(const short8*)(ldsM + lm * 1272 + ks * 40 + q * 8);
            acc2 = __builtin_amdgcn_mfma_f32_16x16x32_bf16(wf[ks], mf, acc2, 0, 0, 0);
        }

        const int j = bj * 4 + jb;
        float4 o;
        o.x = acc2[0] + bo4.x;
        o.y = acc2[1] + bo4.y;
        o.z = acc2[2] + bo4.z;
        o.w = acc2[3] + bo4.w;
        *(float4*)(out + ((size_t)(i * 256 + j)) * 64 + w * 16 + q * 4) = o;
        __syncthreads();  // protect LDS before next tile's writes
    }
}

// ---------------------------------------------------------------------------
extern "C" void kernel_launch(void* const* d_in, const int* in_sizes, int n_in,
                              void* d_out, int out_size, void* d_ws, size_t ws_size,
                              hipStream_t stream) {
    const float* msa  = (const float*)d_in[0];
    const float* ln_w = (const float*)d_in[1];
    const float* ln_b = (const float*)d_in[2];
    const float* wa   = (const float*)d_in[3];
    const float* ba   = (const float*)d_in[4];
    const float* wb   = (const float*)d_in[5];
    const float* bb   = (const float*)d_in[6];
    const float* wo   = (const float*)d_in[7];
    const float* bo   = (const float*)d_in[8];
    float* out = (float*)d_out;

    // workspace (bf16): a (1 MB) | b (1 MB) | woT (128 KB) | wabT (8 KB)
    unsigned short* a_ws = (unsigned short*)d_ws;
    unsigned short* b_ws = a_ws + 256 * 32 * 64;
    unsigned short* woT  = b_ws + 256 * 32 * 64;
    unsigned short* wabT = woT + 64 * 1024;

    prep_w<<<272, 256, 0, stream>>>(wo, wa, wb, woT, wabT);
    prep_ab<<<256, 256, 0, stream>>>(msa, ln_w, ln_b, ba, bb, wabT, a_ws, b_ws);
    fused_opm<<<512, 256, 0, stream>>>(a_ws, b_ws, woT, bo, out);
}